// Round 14
// baseline (135.362 us; speedup 1.0000x reference)
//
#include <hip/hip_runtime.h>
#include <hip/hip_bf16.h>

// Net_27358941675610: the 50-step scan collapses to its fixed point:
//   R   = 0.35*sigmoid((6/7)*(psp^T @ W_h^T + b_h))            [4096,2048]
//   out = 0.35*sigmoid(0.75*(R @ W_o^T + b_o) + 0.125*label)   [4096,512]
// Inputs fp32, output fp32. Internal: bf16 MFMA, fp32 acc.
// R14: GEMM2 ported to the R13-proven 32x32x16 structure (64x64 tile,
// 4 waves of 32x32, BK=64). LDS per kFLOP: 140 -> 91.6 B (GEMM2 was the
// LDS hog: 1.18 GB total vs GEMM1's 0.79 GB). GEMM1 = R13 verbatim.

typedef __bf16 bf16_t;
typedef __bf16 bf16x8 __attribute__((ext_vector_type(8)));
typedef __bf16 bf16x4v __attribute__((ext_vector_type(4)));
typedef float f32x4 __attribute__((ext_vector_type(4)));
typedef float f32x16 __attribute__((ext_vector_type(16)));

#define GLD_TO_LDS16(gp, lp)                                            \
  __builtin_amdgcn_global_load_lds(                                     \
      (__attribute__((address_space(1))) void*)(void*)(gp),             \
      (__attribute__((address_space(3))) void*)(lp), 16, 0, 0)

// ---- prep: psp transpose+cvt AND both weight cvts, one kernel ------------
__global__ __launch_bounds__(256) void prep(
    const float* __restrict__ psp, bf16_t* __restrict__ pspT,
    const float4* __restrict__ w1, bf16x4v* __restrict__ o1, int n1,
    const float4* __restrict__ w2, bf16x4v* __restrict__ o2, int n2) {
  __shared__ float tile[64][65];
  const int tid = threadIdx.x;
  const int b = blockIdx.x;
  const int c0 = (b & 63) * 64;   // batch dim
  const int r0 = (b >> 6) * 64;   // in dim
  const int tx = tid & 63;
  const int ty = tid >> 6;
#pragma unroll
  for (int i = 0; i < 16; ++i) {
    const int r = ty + i * 4;
    tile[r][tx] = psp[(size_t)(r0 + r) * 4096 + c0 + tx];
  }
  const int base = b * 768 + tid;
#pragma unroll
  for (int i = 0; i < 3; ++i) {
    const int idx = base + i * 256;
    const float4 v = (idx < n1) ? w1[idx] : w2[idx - n1];
    bf16x4v o;
    o.x = (bf16_t)v.x; o.y = (bf16_t)v.y; o.z = (bf16_t)v.z; o.w = (bf16_t)v.w;
    if (idx < n1) o1[idx] = o;
    else if (idx - n1 < n2) o2[idx - n1] = o;
  }
  __syncthreads();
#pragma unroll
  for (int i = 0; i < 16; ++i) {
    const int r = ty + i * 4;
    pspT[(size_t)(c0 + r) * 1024 + r0 + tx] = (bf16_t)tile[tx][r];
  }
}

// ---- GEMM1: R(bf16) = 0.35*sigmoid(6/7*(A @ Bt^T + bias)) ----------------
// R13 verbatim (proven). mfma_32x32x16, 128x128 tile, 4 waves of 64x64.
__global__ __launch_bounds__(256, 2) void gemm1_nt(
    const bf16_t* __restrict__ A, const bf16_t* __restrict__ Bt,
    const float* __restrict__ bias, bf16_t* __restrict__ C,
    int M, int N, int K) {
  constexpr int BK = 64;
  __shared__ __align__(16) bf16_t sA[128 * BK];  // 16 KB
  __shared__ __align__(16) bf16_t sB[128 * BK];  // 16 KB

  const int tid = threadIdx.x;
  const int wave = tid >> 6;  // 0..3
  const int lane = tid & 63;
  const int bm = blockIdx.x * 128;
  const int bn = blockIdx.y * 128;
  const int wm = (wave & 1) * 64;
  const int wn = (wave >> 1) * 64;

  f32x16 acc[2][2] = {};

  const int srow8 = lane >> 3;
  const int gseg = (lane & 7) ^ srow8;
  const bf16_t* Ag = A + (size_t)(bm + wave * 32 + srow8) * K + gseg * 8;
  const bf16_t* Bg = Bt + (size_t)(bn + wave * 32 + srow8) * K + gseg * 8;
  const int dst = wave * 2048;

  const int col = lane & 31;
  const int g = lane >> 5;

  for (int k0 = 0; k0 < K; k0 += BK) {
#pragma unroll
    for (int c = 0; c < 4; ++c) {
      GLD_TO_LDS16(Ag + (size_t)(c * 8) * K + k0, sA + dst + c * 512);
      GLD_TO_LDS16(Bg + (size_t)(c * 8) * K + k0, sB + dst + c * 512);
    }
    __syncthreads();

#pragma unroll
    for (int ks = 0; ks < 4; ++ks) {
      const int q = ks * 2 + g;
      bf16x8 av[2], bv[2];
#pragma unroll
      for (int i = 0; i < 2; ++i) {
        const int rr = wm + i * 32 + col;
        av[i] = *(const bf16x8*)(sA + rr * BK + ((q ^ (rr & 7)) * 8));
      }
#pragma unroll
      for (int j = 0; j < 2; ++j) {
        const int rr = wn + j * 32 + col;
        bv[j] = *(const bf16x8*)(sB + rr * BK + ((q ^ (rr & 7)) * 8));
      }
#pragma unroll
      for (int i = 0; i < 2; ++i)
#pragma unroll
        for (int j = 0; j < 2; ++j)
          acc[i][j] = __builtin_amdgcn_mfma_f32_32x32x16_bf16(
              av[i], bv[j], acc[i][j], 0, 0, 0);
    }
    __syncthreads();
  }

  const int rbase = 4 * g;
#pragma unroll
  for (int j = 0; j < 2; ++j) {
    const int gn = bn + wn + j * 32 + col;
    const float bj = bias[gn];
#pragma unroll
    for (int i = 0; i < 2; ++i) {
#pragma unroll
      for (int r = 0; r < 16; ++r) {
        const int gm = bm + wm + i * 32 + (r & 3) + 8 * (r >> 2) + rbase;
        const float z = 0.8571428571428571f * (acc[i][j][r] + bj);
        C[(size_t)gm * N + gn] = (bf16_t)(0.35f / (1.0f + __expf(-z)));
      }
    }
  }
}

// ---- GEMM2: out(fp32) = 0.35*sigmoid(0.75*(R @ Wo^T + b_o) + 0.125*lbl) --
// mfma_32x32x16. 64x64 tile, 4 waves of one 32x32 quadrant, BK=64,
// grid (64,8)=512 -> 2 blk/CU, LDS 16KB. Staging = R6-GEMM2 proven pattern.
__global__ __launch_bounds__(256, 4) void gemm2_nt(
    const bf16_t* __restrict__ A, const bf16_t* __restrict__ Bt,
    const float* __restrict__ bias, const float* __restrict__ lbl,
    float* __restrict__ out, int M, int N, int K) {
  constexpr int BK = 64;
  __shared__ __align__(16) bf16_t sA[64 * BK];  // 8 KB
  __shared__ __align__(16) bf16_t sB[64 * BK];  // 8 KB

  const int tid = threadIdx.x;
  const int wave = tid >> 6;  // 0..3
  const int lane = tid & 63;
  const int bm = blockIdx.x * 64;
  const int bn = blockIdx.y * 64;
  const int wm = (wave & 1) * 32;
  const int wn = (wave >> 1) * 32;

  f32x16 acc = {};

  // staging: wave w stages A rows w*16..+15 and B rows w*16..+15 (2 chunks
  // of 8 rows each); lane l -> chunk row l>>3, LDS seg l&7,
  // global seg (l&7)^(l>>3). (R6-proven.)
  const int srow8 = lane >> 3;
  const int sseg0 = lane & 7;
  bf16_t* sAw = sA + wave * 1024;
  bf16_t* sBw = sB + wave * 1024;

  const int col = lane & 31;
  const int g = lane >> 5;

  for (int k0 = 0; k0 < K; k0 += BK) {
#pragma unroll
    for (int c = 0; c < 2; ++c) {
      const int row = (wave * 2 + c) * 8 + srow8;
      const int gseg = sseg0 ^ (row & 7);
      GLD_TO_LDS16(A + (size_t)(bm + row) * K + k0 + gseg * 8,
                   sAw + c * 512);
      GLD_TO_LDS16(Bt + (size_t)(bn + row) * K + k0 + gseg * 8,
                   sBw + c * 512);
    }
    __syncthreads();

#pragma unroll
    for (int ks = 0; ks < 4; ++ks) {  // four K=16 steps per BK=64
      const int q = ks * 2 + g;
      const int ra = wm + col;
      const int rb = wn + col;
      const bf16x8 av = *(const bf16x8*)(sA + ra * BK + ((q ^ (ra & 7)) * 8));
      const bf16x8 bv = *(const bf16x8*)(sB + rb * BK + ((q ^ (rb & 7)) * 8));
      acc = __builtin_amdgcn_mfma_f32_32x32x16_bf16(av, bv, acc, 0, 0, 0);
    }
    __syncthreads();
  }

  // epilogue: col = lane&31, row = (r&3) + 8*(r>>2) + 4*g  (m74/m101)
  const int gn = bn + wn + col;
  const float bj = bias[gn];
  const int rbase = 4 * g;
#pragma unroll
  for (int r = 0; r < 16; ++r) {
    const int gm = bm + wm + (r & 3) + 8 * (r >> 2) + rbase;
    const float z = 0.75f * (acc[r] + bj) + 0.125f * lbl[(size_t)gm * N + gn];
    out[(size_t)gm * N + gn] = 0.35f / (1.0f + __expf(-z));
  }
}

extern "C" void kernel_launch(void* const* d_in, const int* in_sizes, int n_in,
                              void* d_out, int out_size, void* d_ws, size_t ws_size,
                              hipStream_t stream) {
  constexpr int IN = 1024, HID = 2048, OUT = 512, B = 4096;
  const float* psp = (const float*)d_in[0];   // [IN, B]
  const float* lbl = (const float*)d_in[1];   // [B, OUT]
  const float* W_h = (const float*)d_in[2];   // [HID, IN]
  const float* b_h = (const float*)d_in[3];   // [HID]
  const float* W_o = (const float*)d_in[4];   // [OUT, HID]
  const float* b_o = (const float*)d_in[5];   // [OUT]
  float* out = (float*)d_out;                 // [B, OUT] fp32

  bf16_t* Whb = (bf16_t*)d_ws;                 // [HID, IN]  4 MB
  bf16_t* Wob = Whb + (size_t)HID * IN;        // [OUT, HID] 2 MB
  bf16_t* pspT = Wob + (size_t)OUT * HID;      // [B, IN]    8 MB
  bf16_t* Rm = pspT + (size_t)B * IN;          // [B, HID]  16 MB

  prep<<<1024, 256, 0, stream>>>(
      psp, pspT, (const float4*)W_h, (bf16x4v*)Whb, HID * IN / 4,
      (const float4*)W_o, (bf16x4v*)Wob, OUT * HID / 4);
  gemm1_nt<<<dim3(B / 128, HID / 128), 256, 0, stream>>>(
      pspT, Whb, b_h, Rm, B, HID, IN);
  gemm2_nt<<<dim3(B / 64, OUT / 64), 256, 0, stream>>>(
      Rm, Wob, b_o, lbl, out, B, OUT, HID);
}

// Round 15
// 130.297 us; speedup vs baseline: 1.0389x; 1.0389x over previous
//
#include <hip/hip_runtime.h>
#include <hip/hip_bf16.h>

// Net_27358941675610: the 50-step scan collapses to its fixed point:
//   R   = 0.35*sigmoid((6/7)*(psp^T @ W_h^T + b_h))            [4096,2048]
//   out = 0.35*sigmoid(0.75*(R @ W_o^T + b_o) + 0.125*label)   [4096,512]
// Inputs fp32, output fp32. Internal: bf16 MFMA, fp32 acc.
// R15 = R13 re-land (session best, 132.2us). R14's GEMM2 32x32 port cut
// occupancy 4->2 blk/CU and regressed; occupancy > LDS-bytes in this regime.
// GEMM1: mfma_32x32x16, 128x128 tile, 4 waves of 64x64, BK=64 (R13-proven).
// GEMM2: mfma_16x16x32, 32x64 tile, 4 waves of 16x32, grid 1024 (R10-proven).

typedef __bf16 bf16_t;
typedef __bf16 bf16x8 __attribute__((ext_vector_type(8)));
typedef __bf16 bf16x4v __attribute__((ext_vector_type(4)));
typedef float f32x4 __attribute__((ext_vector_type(4)));
typedef float f32x16 __attribute__((ext_vector_type(16)));

#define GLD_TO_LDS16(gp, lp)                                            \
  __builtin_amdgcn_global_load_lds(                                     \
      (__attribute__((address_space(1))) void*)(void*)(gp),             \
      (__attribute__((address_space(3))) void*)(lp), 16, 0, 0)

// ---- prep: psp transpose+cvt AND both weight cvts, one kernel ------------
__global__ __launch_bounds__(256) void prep(
    const float* __restrict__ psp, bf16_t* __restrict__ pspT,
    const float4* __restrict__ w1, bf16x4v* __restrict__ o1, int n1,
    const float4* __restrict__ w2, bf16x4v* __restrict__ o2, int n2) {
  __shared__ float tile[64][65];
  const int tid = threadIdx.x;
  const int b = blockIdx.x;
  const int c0 = (b & 63) * 64;   // batch dim
  const int r0 = (b >> 6) * 64;   // in dim
  const int tx = tid & 63;
  const int ty = tid >> 6;
#pragma unroll
  for (int i = 0; i < 16; ++i) {
    const int r = ty + i * 4;
    tile[r][tx] = psp[(size_t)(r0 + r) * 4096 + c0 + tx];
  }
  const int base = b * 768 + tid;
#pragma unroll
  for (int i = 0; i < 3; ++i) {
    const int idx = base + i * 256;
    const float4 v = (idx < n1) ? w1[idx] : w2[idx - n1];
    bf16x4v o;
    o.x = (bf16_t)v.x; o.y = (bf16_t)v.y; o.z = (bf16_t)v.z; o.w = (bf16_t)v.w;
    if (idx < n1) o1[idx] = o;
    else if (idx - n1 < n2) o2[idx - n1] = o;
  }
  __syncthreads();
#pragma unroll
  for (int i = 0; i < 16; ++i) {
    const int r = ty + i * 4;
    pspT[(size_t)(c0 + r) * 1024 + r0 + tx] = (bf16_t)tile[tx][r];
  }
}

// ---- GEMM1: R(bf16) = 0.35*sigmoid(6/7*(A @ Bt^T + bias)) ----------------
// mfma_f32_32x32x16_bf16. 128x128 tile, 4 waves of 64x64 (2x2 of 32x32),
// BK=64, single-buffer LDS 32KB, grid (32,16)=512 -> 2 blocks/CU.
__global__ __launch_bounds__(256, 2) void gemm1_nt(
    const bf16_t* __restrict__ A, const bf16_t* __restrict__ Bt,
    const float* __restrict__ bias, bf16_t* __restrict__ C,
    int M, int N, int K) {
  constexpr int BK = 64;
  __shared__ __align__(16) bf16_t sA[128 * BK];  // 16 KB
  __shared__ __align__(16) bf16_t sB[128 * BK];  // 16 KB

  const int tid = threadIdx.x;
  const int wave = tid >> 6;  // 0..3
  const int lane = tid & 63;
  const int bm = blockIdx.x * 128;
  const int bn = blockIdx.y * 128;
  const int wm = (wave & 1) * 64;
  const int wn = (wave >> 1) * 64;

  f32x16 acc[2][2] = {};

  const int srow8 = lane >> 3;
  const int gseg = (lane & 7) ^ srow8;
  const bf16_t* Ag = A + (size_t)(bm + wave * 32 + srow8) * K + gseg * 8;
  const bf16_t* Bg = Bt + (size_t)(bn + wave * 32 + srow8) * K + gseg * 8;
  const int dst = wave * 2048;

  const int col = lane & 31;
  const int g = lane >> 5;

  for (int k0 = 0; k0 < K; k0 += BK) {
#pragma unroll
    for (int c = 0; c < 4; ++c) {
      GLD_TO_LDS16(Ag + (size_t)(c * 8) * K + k0, sA + dst + c * 512);
      GLD_TO_LDS16(Bg + (size_t)(c * 8) * K + k0, sB + dst + c * 512);
    }
    __syncthreads();

#pragma unroll
    for (int ks = 0; ks < 4; ++ks) {
      const int q = ks * 2 + g;
      bf16x8 av[2], bv[2];
#pragma unroll
      for (int i = 0; i < 2; ++i) {
        const int rr = wm + i * 32 + col;
        av[i] = *(const bf16x8*)(sA + rr * BK + ((q ^ (rr & 7)) * 8));
      }
#pragma unroll
      for (int j = 0; j < 2; ++j) {
        const int rr = wn + j * 32 + col;
        bv[j] = *(const bf16x8*)(sB + rr * BK + ((q ^ (rr & 7)) * 8));
      }
#pragma unroll
      for (int i = 0; i < 2; ++i)
#pragma unroll
        for (int j = 0; j < 2; ++j)
          acc[i][j] = __builtin_amdgcn_mfma_f32_32x32x16_bf16(
              av[i], bv[j], acc[i][j], 0, 0, 0);
    }
    __syncthreads();
  }

  // epilogue: col = lane&31, row = (r&3) + 8*(r>>2) + 4*(lane>>5) [m74/m101]
  const int rbase = 4 * g;
#pragma unroll
  for (int j = 0; j < 2; ++j) {
    const int gn = bn + wn + j * 32 + col;
    const float bj = bias[gn];
#pragma unroll
    for (int i = 0; i < 2; ++i) {
#pragma unroll
      for (int r = 0; r < 16; ++r) {
        const int gm = bm + wm + i * 32 + (r & 3) + 8 * (r >> 2) + rbase;
        const float z = 0.8571428571428571f * (acc[i][j][r] + bj);
        C[(size_t)gm * N + gn] = (bf16_t)(0.35f / (1.0f + __expf(-z)));
      }
    }
  }
}

// ---- GEMM2: out(fp32) = 0.35*sigmoid(0.75*(R @ Wo^T + b_o) + 0.125*lbl) --
// R10 verbatim (proven). 32x64 tile, 4 waves of 16x32, BK=64, grid 1024.
__global__ __launch_bounds__(256, 4) void gemm2_nt(
    const bf16_t* __restrict__ A, const bf16_t* __restrict__ Bt,
    const float* __restrict__ bias, const float* __restrict__ lbl,
    float* __restrict__ out, int M, int N, int K) {
  constexpr int BK = 64;
  __shared__ __align__(16) bf16_t sA[32 * BK];  // 4 KB
  __shared__ __align__(16) bf16_t sB[64 * BK];  // 8 KB

  const int tid = threadIdx.x;
  const int wave = tid >> 6;
  const int lane = tid & 63;
  const int bm = blockIdx.x * 32;
  const int bn = blockIdx.y * 64;
  const int wm = (wave & 1) * 16;
  const int wn = (wave >> 1) * 32;

  f32x4 acc[2] = {};

  const int srow8 = lane >> 3;
  const int gseg = (lane & 7) ^ srow8;
  const bf16_t* Ag = A + (size_t)(bm + wave * 8 + srow8) * K + gseg * 8;
  const bf16_t* Bg = Bt + (size_t)(bn + wave * 16 + srow8) * K + gseg * 8;
  const int dstA = wave * 512;
  const int dstB = wave * 1024;

  const int fr = lane & 15;
  const int qh = lane >> 4;

  for (int k0 = 0; k0 < K; k0 += BK) {
    GLD_TO_LDS16(Ag + k0, sA + dstA);
#pragma unroll
    for (int c = 0; c < 2; ++c)
      GLD_TO_LDS16(Bg + (size_t)(c * 8) * K + k0, sB + dstB + c * 512);
    __syncthreads();

#pragma unroll
    for (int ks = 0; ks < 2; ++ks) {
      const int q = ks * 4 + qh;
      const int ra = wm + fr;
      const bf16x8 av = *(const bf16x8*)(sA + ra * BK + ((q ^ (ra & 7)) * 8));
      bf16x8 bv[2];
#pragma unroll
      for (int j = 0; j < 2; ++j) {
        const int rr = wn + j * 16 + fr;
        bv[j] = *(const bf16x8*)(sB + rr * BK + ((q ^ (rr & 7)) * 8));
      }
#pragma unroll
      for (int j = 0; j < 2; ++j)
        acc[j] = __builtin_amdgcn_mfma_f32_16x16x32_bf16(av, bv[j], acc[j],
                                                         0, 0, 0);
    }
    __syncthreads();
  }

  const int cm0 = (lane >> 4) * 4;
#pragma unroll
  for (int j = 0; j < 2; ++j) {
    const int gn = bn + wn + j * 16 + fr;
    const float bj = bias[gn];
#pragma unroll
    for (int r = 0; r < 4; ++r) {
      const int gm = bm + wm + cm0 + r;
      const float z =
          0.75f * (acc[j][r] + bj) + 0.125f * lbl[(size_t)gm * N + gn];
      out[(size_t)gm * N + gn] = 0.35f / (1.0f + __expf(-z));
    }
  }
}

extern "C" void kernel_launch(void* const* d_in, const int* in_sizes, int n_in,
                              void* d_out, int out_size, void* d_ws, size_t ws_size,
                              hipStream_t stream) {
  constexpr int IN = 1024, HID = 2048, OUT = 512, B = 4096;
  const float* psp = (const float*)d_in[0];   // [IN, B]
  const float* lbl = (const float*)d_in[1];   // [B, OUT]
  const float* W_h = (const float*)d_in[2];   // [HID, IN]
  const float* b_h = (const float*)d_in[3];   // [HID]
  const float* W_o = (const float*)d_in[4];   // [OUT, HID]
  const float* b_o = (const float*)d_in[5];   // [OUT]
  float* out = (float*)d_out;                 // [B, OUT] fp32

  bf16_t* Whb = (bf16_t*)d_ws;                 // [HID, IN]  4 MB
  bf16_t* Wob = Whb + (size_t)HID * IN;        // [OUT, HID] 2 MB
  bf16_t* pspT = Wob + (size_t)OUT * HID;      // [B, IN]    8 MB
  bf16_t* Rm = pspT + (size_t)B * IN;          // [B, HID]  16 MB

  prep<<<1024, 256, 0, stream>>>(
      psp, pspT, (const float4*)W_h, (bf16x4v*)Whb, HID * IN / 4,
      (const float4*)W_o, (bf16x4v*)Wob, OUT * HID / 4);
  gemm1_nt<<<dim3(B / 128, HID / 128), 256, 0, stream>>>(
      pspT, Whb, b_h, Rm, B, HID, IN);
  gemm2_nt<<<dim3(B / 32, OUT / 64), 256, 0, stream>>>(
      Rm, Wob, b_o, lbl, out, B, OUT, HID);
}